// Round 1
// baseline (293.136 us; speedup 1.0000x reference)
//
#include <hip/hip_runtime.h>
#include <hip/hip_bf16.h>

// Reference: out = sum(softmax(sim, axis=2), axis=2) == 1.0 identically.
// The whole einsum/softmax cancels; output is ones((B=64, Lc=2048, 1)).
// Kernel just fills d_out with 1.0f using float4 stores.

__global__ void __launch_bounds__(256) fill_ones_kernel(float4* __restrict__ out, int n4) {
    int i = blockIdx.x * blockDim.x + threadIdx.x;
    if (i < n4) {
        out[i] = make_float4(1.0f, 1.0f, 1.0f, 1.0f);
    }
}

__global__ void __launch_bounds__(256) fill_ones_tail_kernel(float* __restrict__ out, int start, int n) {
    int i = start + blockIdx.x * blockDim.x + threadIdx.x;
    if (i < n) {
        out[i] = 1.0f;
    }
}

extern "C" void kernel_launch(void* const* d_in, const int* in_sizes, int n_in,
                              void* d_out, int out_size, void* d_ws, size_t ws_size,
                              hipStream_t stream) {
    (void)d_in; (void)in_sizes; (void)n_in; (void)d_ws; (void)ws_size;
    float* out = (float*)d_out;

    int n4 = out_size / 4;                 // 131072/4 = 32768 float4s
    if (n4 > 0) {
        int threads = 256;
        int blocks = (n4 + threads - 1) / threads;   // 128 blocks
        fill_ones_kernel<<<blocks, threads, 0, stream>>>((float4*)out, n4);
    }
    int rem_start = n4 * 4;
    int rem = out_size - rem_start;        // 0 for out_size=131072
    if (rem > 0) {
        fill_ones_tail_kernel<<<1, 256, 0, stream>>>(out, rem_start, out_size);
    }
}